// Round 1
// baseline (1485.933 us; speedup 1.0000x reference)
//
#include <hip/hip_runtime.h>
#include <math.h>

// Problem constants: B=2, S=2048, H=1024, NH=16, HD=64
#define Bb  2
#define Ss  2048
#define Hh  1024
#define NHh 16
#define HDd 64

__device__ __forceinline__ float row_max16(float v) {
#pragma unroll
  for (int m = 1; m < 16; m <<= 1) v = fmaxf(v, __shfl_xor(v, m, 16));
  return v;
}
__device__ __forceinline__ float row_sum16(float v) {
#pragma unroll
  for (int m = 1; m < 16; m <<= 1) v += __shfl_xor(v, m, 16);
  return v;
}

// C[M,N] = X[M,K] @ W[N,K]^T + bias[N]   (NT gemm, both operands K-contiguous)
// qkv_mode=1: scatter-store into (B, NH, S, HD) layout. M=4096,N=1024,K=1024 fixed.
__global__ __launch_bounds__(256) void gemm_nt(
    const float* __restrict__ X, const float* __restrict__ W,
    const float* __restrict__ bias, float* __restrict__ out, int qkv_mode)
{
  const int N = 1024, K = 1024;
  __shared__ float Xs[16][68];   // [k][i], pad 68 keeps float4 alignment (272B rows)
  __shared__ float Ws[16][68];   // [k][j]
  const int tid = threadIdx.x;
  const int tx = tid & 15, ty = tid >> 4;
  const int i0 = blockIdx.y * 64, j0 = blockIdx.x * 64;
  const int lr = tid >> 2;          // 0..63 tile row
  const int lk = (tid & 3) << 2;    // 0,4,8,12
  const float* Xp = X + (size_t)(i0 + lr) * K + lk;
  const float* Wp = W + (size_t)(j0 + lr) * K + lk;
  float acc[4][4] = {};
  for (int k0 = 0; k0 < K; k0 += 16) {
    const float4 xv = *(const float4*)(Xp + k0);
    const float4 wv = *(const float4*)(Wp + k0);
    __syncthreads();   // previous iteration's reads done before overwrite
    Xs[lk+0][lr]=xv.x; Xs[lk+1][lr]=xv.y; Xs[lk+2][lr]=xv.z; Xs[lk+3][lr]=xv.w;
    Ws[lk+0][lr]=wv.x; Ws[lk+1][lr]=wv.y; Ws[lk+2][lr]=wv.z; Ws[lk+3][lr]=wv.w;
    __syncthreads();
#pragma unroll
    for (int kk = 0; kk < 16; ++kk) {
      const float4 a = *(const float4*)&Xs[kk][ty*4];
      const float4 b = *(const float4*)&Ws[kk][tx*4];
      const float av[4] = {a.x,a.y,a.z,a.w};
      const float bv[4] = {b.x,b.y,b.z,b.w};
#pragma unroll
      for (int r = 0; r < 4; ++r)
#pragma unroll
        for (int c = 0; c < 4; ++c)
          acc[r][c] = fmaf(av[r], bv[c], acc[r][c]);
    }
  }
  const float4 bj = *(const float4*)(bias + j0 + tx*4);
  const float bjv[4] = {bj.x,bj.y,bj.z,bj.w};
#pragma unroll
  for (int r = 0; r < 4; ++r) {
    const int i = i0 + ty*4 + r;
    float4 o;
    o.x = acc[r][0]+bjv[0]; o.y = acc[r][1]+bjv[1];
    o.z = acc[r][2]+bjv[2]; o.w = acc[r][3]+bjv[3];
    if (qkv_mode) {
      const int b = i >> 11, s = i & (Ss - 1);   // S = 2048
      const int h = j0 >> 6;                     // N-tile == head (HD=64)
      *(float4*)(out + ((size_t)((b*NHh + h)*Ss + s))*HDd + tx*4) = o;
    } else {
      *(float4*)(out + (size_t)i*N + j0 + tx*4) = o;
    }
  }
}

// Flash-style fp32 attention. Grid: (S/64 q-tiles, B*NH). Block 256.
// Q,K,V in (B*NH, S, HD). ctx out in (B*S, H) row-major for the O-projection.
__global__ __launch_bounds__(256) void attn_kernel(
    const float* __restrict__ Q, const float* __restrict__ Kt,
    const float* __restrict__ V, const float* __restrict__ bias,
    const int* __restrict__ kpm, float* __restrict__ ctx)
{
  __shared__ float Qs[64][68];    // [d][i] (transposed)
  __shared__ float KPs[64][68];   // phase A: K transposed [d][j]; phase B: P [i][k]
  __shared__ float Vs[64][68];    // [k][d]
  const int tid = threadIdx.x;
  const int tx = tid & 15, ty = tid >> 4;
  const int bh = blockIdx.y;
  const int b = bh >> 4, h = bh & 15;
  const int q0 = blockIdx.x * 64;
  const float scale = 0.125f;     // HD^-0.5

  // Load Q tile once, transposed into LDS
#pragma unroll
  for (int it = 0; it < 4; ++it) {
    const int idx = tid + it*256;
    const int row = idx >> 4;
    const int dq  = (idx & 15) * 4;
    const float4 qv = *(const float4*)(Q + ((size_t)bh*Ss + q0 + row)*HDd + dq);
    Qs[dq+0][row]=qv.x; Qs[dq+1][row]=qv.y; Qs[dq+2][row]=qv.z; Qs[dq+3][row]=qv.w;
  }

  float O[4][4] = {};
  float m_prev[4] = {-INFINITY,-INFINITY,-INFINITY,-INFINITY};
  float l[4] = {};

  for (int k0 = 0; k0 < Ss; k0 += 64) {
    __syncthreads();   // prev PV done with KPs/Vs
#pragma unroll
    for (int it = 0; it < 4; ++it) {
      const int idx = tid + it*256;
      const int row = idx >> 4;
      const int dq  = (idx & 15) * 4;
      const float4 kv = *(const float4*)(Kt + ((size_t)bh*Ss + k0 + row)*HDd + dq);
      KPs[dq+0][row]=kv.x; KPs[dq+1][row]=kv.y; KPs[dq+2][row]=kv.z; KPs[dq+3][row]=kv.w;
      const float4 vv = *(const float4*)(V + ((size_t)bh*Ss + k0 + row)*HDd + dq);
      *(float4*)&Vs[row][dq] = vv;
    }
    __syncthreads();

    // S_tile = Q @ K^T
    float sc[4][4] = {};
#pragma unroll 16
    for (int dd = 0; dd < 64; ++dd) {
      const float4 a = *(const float4*)&Qs[dd][ty*4];
      const float4 kb = *(const float4*)&KPs[dd][tx*4];
      const float av[4] = {a.x,a.y,a.z,a.w};
      const float bv[4] = {kb.x,kb.y,kb.z,kb.w};
#pragma unroll
      for (int r = 0; r < 4; ++r)
#pragma unroll
        for (int c = 0; c < 4; ++c)
          sc[r][c] = fmaf(av[r], bv[c], sc[r][c]);
    }

    // bias + mask + online softmax (row stats replicated across the 16-lane row group)
    const int4 mk = *(const int4*)(kpm + b*Ss + k0 + tx*4);
    const int mkv[4] = {mk.x, mk.y, mk.z, mk.w};
    float p[4][4];
    float alpha[4];
#pragma unroll
    for (int r = 0; r < 4; ++r) {
      const int qg = q0 + ty*4 + r;
      const float4 bv = *(const float4*)(bias + ((size_t)h*Ss + qg)*Ss + k0 + tx*4);
      float s0 = mkv[0] ? -INFINITY : fmaf(sc[r][0], scale, bv.x);
      float s1 = mkv[1] ? -INFINITY : fmaf(sc[r][1], scale, bv.y);
      float s2 = mkv[2] ? -INFINITY : fmaf(sc[r][2], scale, bv.z);
      float s3 = mkv[3] ? -INFINITY : fmaf(sc[r][3], scale, bv.w);
      float mt = row_max16(fmaxf(fmaxf(s0,s1), fmaxf(s2,s3)));
      const float mn = fmaxf(m_prev[r], mt);
      alpha[r] = expf(m_prev[r] - mn);   // first tile: exp(-inf)=0
      p[r][0] = expf(s0 - mn); p[r][1] = expf(s1 - mn);
      p[r][2] = expf(s2 - mn); p[r][3] = expf(s3 - mn);
      const float rs = row_sum16(p[r][0]+p[r][1]+p[r][2]+p[r][3]);
      l[r] = l[r]*alpha[r] + rs;
      m_prev[r] = mn;
    }

    __syncthreads();   // everyone done reading K from KPs
#pragma unroll
    for (int r = 0; r < 4; ++r) {
      const float4 pv = {p[r][0], p[r][1], p[r][2], p[r][3]};
      *(float4*)&KPs[ty*4+r][tx*4] = pv;   // P in [i][k]
    }
    __syncthreads();

#pragma unroll
    for (int r = 0; r < 4; ++r)
#pragma unroll
      for (int c = 0; c < 4; ++c) O[r][c] *= alpha[r];

    // O += P @ V
#pragma unroll 16
    for (int kk = 0; kk < 64; ++kk) {
      const float4 vv = *(const float4*)&Vs[kk][tx*4];
      const float vvv[4] = {vv.x,vv.y,vv.z,vv.w};
      const float pk[4] = {KPs[ty*4+0][kk], KPs[ty*4+1][kk],
                           KPs[ty*4+2][kk], KPs[ty*4+3][kk]};
#pragma unroll
      for (int r = 0; r < 4; ++r)
#pragma unroll
        for (int c = 0; c < 4; ++c)
          O[r][c] = fmaf(pk[r], vvv[c], O[r][c]);
    }
  }

#pragma unroll
  for (int r = 0; r < 4; ++r) {
    const float inv = 1.0f / fmaxf(l[r], 1e-6f);
    const int qg = q0 + ty*4 + r;
    const float4 o = {O[r][0]*inv, O[r][1]*inv, O[r][2]*inv, O[r][3]*inv};
    *(float4*)(ctx + ((size_t)(b*Ss + qg))*Hh + h*HDd + tx*4) = o;
  }
}

extern "C" void kernel_launch(void* const* d_in, const int* in_sizes, int n_in,
                              void* d_out, int out_size, void* d_ws, size_t ws_size,
                              hipStream_t stream) {
  const float* query = (const float*)d_in[0];
  const float* key   = (const float*)d_in[1];
  const float* value = (const float*)d_in[2];
  const int*   kpm   = (const int*)d_in[3];
  const float* bias  = (const float*)d_in[4];
  const float* q_w   = (const float*)d_in[5];
  const float* q_b   = (const float*)d_in[6];
  const float* k_w   = (const float*)d_in[7];
  const float* k_b   = (const float*)d_in[8];
  const float* v_w   = (const float*)d_in[9];
  const float* v_b   = (const float*)d_in[10];
  const float* o_w   = (const float*)d_in[11];
  const float* o_b   = (const float*)d_in[12];
  float* out = (float*)d_out;

  const size_t per = (size_t)Bb * NHh * Ss * HDd;   // 4,194,304 floats
  float* q   = (float*)d_ws;
  float* k   = q + per;
  float* v   = k + per;
  float* ctx = v + per;   // total 64 MB of workspace

  const dim3 blk(256);
  const dim3 gproj(Hh/64, (Bb*Ss)/64);   // (16, 64)
  gemm_nt<<<gproj, blk, 0, stream>>>(query, q_w, q_b, q, 1);
  gemm_nt<<<gproj, blk, 0, stream>>>(key,   k_w, k_b, k, 1);
  gemm_nt<<<gproj, blk, 0, stream>>>(value, v_w, v_b, v, 1);

  const dim3 gattn(Ss/64, Bb*NHh);       // (32, 32)
  attn_kernel<<<gattn, blk, 0, stream>>>(q, k, v, bias, kpm, ctx);

  gemm_nt<<<gproj, blk, 0, stream>>>(ctx, o_w, o_b, out, 0);
}

// Round 2
// 920.082 us; speedup vs baseline: 1.6150x; 1.6150x over previous
//
#include <hip/hip_runtime.h>
#include <math.h>

// B=2, S=2048, H=1024, NH=16, HD=64
#define Ss  2048
#define Hh  1024

typedef unsigned short u16;
typedef __attribute__((ext_vector_type(8))) short short8;
typedef __attribute__((ext_vector_type(4))) float fx4;

__device__ __forceinline__ u16 f2bf(float f) {
  unsigned int u = __float_as_uint(f);
  u = (u + 0x7fffu + ((u >> 16) & 1u)) >> 16;
  return (u16)u;
}

__device__ __forceinline__ void gld_lds16(const u16* g, u16* l) {
  __builtin_amdgcn_global_load_lds(
      (const __attribute__((address_space(1))) unsigned int*)(const unsigned int*)g,
      (__attribute__((address_space(3))) unsigned int*)(unsigned int*)l, 16, 0, 0);
}

#define MFMA16(a,b,c) __builtin_amdgcn_mfma_f32_16x16x32_bf16((a),(b),(c),0,0,0)

// ---- casts -----------------------------------------------------------------
__global__ __launch_bounds__(256) void cast3(const float* __restrict__ a,
    const float* __restrict__ b, const float* __restrict__ c,
    u16* __restrict__ oa, u16* __restrict__ ob, u16* __restrict__ oc) {
  const int z = blockIdx.z;
  const float* in = z == 0 ? a : (z == 1 ? b : c);
  u16* out = z == 0 ? oa : (z == 1 ? ob : oc);
  const int i = (blockIdx.x * 256 + threadIdx.x) * 4;
  const float4 v = *(const float4*)(in + i);
  ushort4 r; r.x = f2bf(v.x); r.y = f2bf(v.y); r.z = f2bf(v.z); r.w = f2bf(v.w);
  *(ushort4*)(out + i) = r;
}

__global__ __launch_bounds__(256) void cast4(const float* __restrict__ a,
    const float* __restrict__ b, const float* __restrict__ c, const float* __restrict__ d,
    u16* __restrict__ oa, u16* __restrict__ ob, u16* __restrict__ oc, u16* __restrict__ od) {
  const int z = blockIdx.z;
  const float* in = z == 0 ? a : (z == 1 ? b : (z == 2 ? c : d));
  u16* out = z == 0 ? oa : (z == 1 ? ob : (z == 2 ? oc : od));
  const int i = (blockIdx.x * 256 + threadIdx.x) * 4;
  const float4 v = *(const float4*)(in + i);
  ushort4 r; r.x = f2bf(v.x); r.y = f2bf(v.y); r.z = f2bf(v.z); r.w = f2bf(v.w);
  *(ushort4*)(out + i) = r;
}

// ---- GEMM: C[M,N] = A[M,K]@W[N,K]^T + bias, K=N=1024, 128x128 tile --------
// MODE 0: fp32 out row-major [row*1024+col]
// MODE 1: bf16 out scattered to (B,NH,S,HD); val = (acc+bias)*scale
template <int MODE>
__device__ __forceinline__ void gemm_core(const u16* __restrict__ A,
    const u16* __restrict__ W, const float* __restrict__ bias,
    void* __restrict__ out, float scale) {
  __shared__ __align__(16) u16 As[4096];  // chunks [c0..3][m0..127] * 8 shorts
  __shared__ __align__(16) u16 Bs[4096];
  const int tid = threadIdx.x;
  const int w = tid >> 6, lane = tid & 63, ln = lane & 15, quad = lane >> 4;
  const int i0 = blockIdx.y * 128, j0 = blockIdx.x * 128;
  const int wr = (w & 1) * 64, wc = (w >> 1) * 64;
  fx4 acc[4][4] = {};
  const int L0 = w * 64 + lane, L1 = L0 + 256;
  const u16* sa0 = A + (size_t)(i0 + (L0 & 127)) * 1024 + (L0 >> 7) * 8;
  const u16* sa1 = A + (size_t)(i0 + (L1 & 127)) * 1024 + (L1 >> 7) * 8;
  const u16* sb0 = W + (size_t)(j0 + (L0 & 127)) * 1024 + (L0 >> 7) * 8;
  const u16* sb1 = W + (size_t)(j0 + (L1 & 127)) * 1024 + (L1 >> 7) * 8;
  u16* da0 = As + (w * 64) * 8;  u16* da1 = As + (256 + w * 64) * 8;
  u16* db0 = Bs + (w * 64) * 8;  u16* db1 = Bs + (256 + w * 64) * 8;
  for (int k0 = 0; k0 < 1024; k0 += 32) {
    __syncthreads();
    gld_lds16(sa0 + k0, da0); gld_lds16(sa1 + k0, da1);
    gld_lds16(sb0 + k0, db0); gld_lds16(sb1 + k0, db1);
    __syncthreads();
    short8 a[4], b[4];
#pragma unroll
    for (int t = 0; t < 4; ++t) {
      a[t] = *(const short8*)&As[(quad * 128 + wr + t * 16 + ln) * 8];
      b[t] = *(const short8*)&Bs[(quad * 128 + wc + t * 16 + ln) * 8];
    }
#pragma unroll
    for (int mt = 0; mt < 4; ++mt)
#pragma unroll
      for (int nt = 0; nt < 4; ++nt)
        acc[mt][nt] = MFMA16(a[mt], b[nt], acc[mt][nt]);
  }
#pragma unroll
  for (int nt = 0; nt < 4; ++nt) {
    const int col = j0 + wc + nt * 16 + ln;
    const float bv = bias[col];
#pragma unroll
    for (int mt = 0; mt < 4; ++mt)
#pragma unroll
      for (int r = 0; r < 4; ++r) {
        const int row = i0 + wr + mt * 16 + quad * 4 + r;
        const float val = (acc[mt][nt][r] + bv) * scale;
        if (MODE == 1) {
          const int bb = row >> 11, s = row & 2047, h = col >> 6, d = col & 63;
          ((u16*)out)[((size_t)(bb * 16 + h) * 2048 + s) * 64 + d] = f2bf(val);
        } else {
          ((float*)out)[(size_t)row * 1024 + col] = val;
        }
      }
  }
}

__global__ __launch_bounds__(256) void gemm_qkv(
    const u16* xq, const u16* xk, const u16* xv,
    const u16* wq, const u16* wk, const u16* wv,
    const float* bq, const float* bk, const float* bv,
    u16* q, u16* k, u16* v) {
  const int z = blockIdx.z;
  const u16* A = z == 0 ? xq : (z == 1 ? xk : xv);
  const u16* W = z == 0 ? wq : (z == 1 ? wk : wv);
  const float* bb = z == 0 ? bq : (z == 1 ? bk : bv);
  u16* o = z == 0 ? q : (z == 1 ? k : v);
  const float sc = z == 0 ? 0.125f : 1.0f;  // fold HD^-0.5 into Q
  gemm_core<1>(A, W, bb, o, sc);
}

__global__ __launch_bounds__(256) void gemm_o(const u16* ctx, const u16* wo,
                                              const float* ob, float* out) {
  gemm_core<0>(ctx, wo, ob, out, 1.0f);
}

// ---- V transpose: (bh,S,HD) -> (bh,HD,S), bf16 -----------------------------
__global__ __launch_bounds__(256) void transpose_v(const u16* __restrict__ v,
                                                   u16* __restrict__ vt) {
  __shared__ u16 T[64][72];
  const int tid = threadIdx.x;
  const int bh = blockIdx.y, s0 = blockIdx.x * 64;
#pragma unroll
  for (int i = 0; i < 2; ++i) {
    const int L = i * 256 + tid, key = L >> 3, dc = L & 7;
    const uint4 val = *(const uint4*)&v[((size_t)bh * 2048 + s0 + key) * 64 + dc * 8];
    *(uint4*)&T[key][dc * 8] = val;
  }
  __syncthreads();
#pragma unroll
  for (int i = 0; i < 2; ++i) {
    const int L = i * 256 + tid, d = L >> 3, kc = L & 7;
    u16 tmp[8];
#pragma unroll
    for (int j = 0; j < 8; ++j) tmp[j] = T[kc * 8 + j][d];
    *(uint4*)&vt[((size_t)bh * 64 + d) * 2048 + s0 + kc * 8] = *(const uint4*)tmp;
  }
}

// ---- flash attention: 128 q-rows/block, 64-key tiles, MFMA -----------------
__global__ __launch_bounds__(256) void attn(const u16* __restrict__ Qb,
    const u16* __restrict__ Kb, const u16* __restrict__ VT,
    const float* __restrict__ bias, const int* __restrict__ kpm,
    u16* __restrict__ ctx) {
  __shared__ __align__(16) u16 Ks[4096];  // [c0..7][n0..63]*8
  __shared__ __align__(16) u16 Vs[4096];  // [kc0..7][d0..63]*8
  __shared__ __align__(16) u16 Ps[8192];  // [kc0..7][q0..127]*8
  const int tid = threadIdx.x;
  const int w = tid >> 6, lane = tid & 63, ln = lane & 15, quad = lane >> 4;
  const int q0 = blockIdx.x * 128;
  const int hb = blockIdx.y, h = hb >> 1, b = hb & 1, bh = b * 16 + h;
  const int wr = w * 32;

  short8 qf[2][2];
#pragma unroll
  for (int mt = 0; mt < 2; ++mt)
#pragma unroll
    for (int ks = 0; ks < 2; ++ks)
      qf[mt][ks] = *(const short8*)&Qb[((size_t)bh * 2048 + q0 + wr + mt * 16 + ln) * 64 +
                                       ks * 32 + quad * 8];
  float mi[2][4], li[2][4];
  fx4 O[2][4] = {};
#pragma unroll
  for (int mt = 0; mt < 2; ++mt)
#pragma unroll
    for (int r = 0; r < 4; ++r) { mi[mt][r] = -3.0e38f; li[mt][r] = 0.f; }

  const int L0 = w * 64 + lane, L1 = L0 + 256;
  const u16* sk0 = Kb + ((size_t)bh * 2048 + (L0 & 63)) * 64 + (L0 >> 6) * 8;
  const u16* sk1 = Kb + ((size_t)bh * 2048 + (L1 & 63)) * 64 + (L1 >> 6) * 8;
  const u16* sv0 = VT + ((size_t)bh * 64 + (L0 & 63)) * 2048 + (L0 >> 6) * 8;
  const u16* sv1 = VT + ((size_t)bh * 64 + (L1 & 63)) * 2048 + (L1 >> 6) * 8;
  u16* dk0 = Ks + (w * 64) * 8;  u16* dk1 = Ks + (256 + w * 64) * 8;
  u16* dv0 = Vs + (w * 64) * 8;  u16* dv1 = Vs + (256 + w * 64) * 8;
  const int kcb = ln >> 3, jj = ln & 7;

  for (int kt = 0; kt < Ss; kt += 64) {
    __syncthreads();
    gld_lds16(sk0 + (size_t)kt * 64, dk0);
    gld_lds16(sk1 + (size_t)kt * 64, dk1);
    gld_lds16(sv0 + kt, dv0);
    gld_lds16(sv1 + kt, dv1);
    __syncthreads();

    fx4 S[2][4] = {};
#pragma unroll
    for (int ks = 0; ks < 2; ++ks)
#pragma unroll
      for (int nt = 0; nt < 4; ++nt) {
        const short8 kf = *(const short8*)&Ks[((ks * 4 + quad) * 64 + nt * 16 + ln) * 8];
        S[0][nt] = MFMA16(qf[0][ks], kf, S[0][nt]);
        S[1][nt] = MFMA16(qf[1][ks], kf, S[1][nt]);
      }

    int msk[4];
#pragma unroll
    for (int nt = 0; nt < 4; ++nt) msk[nt] = kpm[b * Ss + kt + nt * 16 + ln];

    float alpha[2][4];
#pragma unroll
    for (int mt = 0; mt < 2; ++mt)
#pragma unroll
      for (int r = 0; r < 4; ++r) {
        const int qg = q0 + wr + mt * 16 + quad * 4 + r;
        const float* bp = bias + (size_t)h * Ss * Ss + (size_t)qg * Ss + kt;
        const float s0 = msk[0] ? -3.0e38f : S[mt][0][r] + bp[ln];
        const float s1 = msk[1] ? -3.0e38f : S[mt][1][r] + bp[16 + ln];
        const float s2 = msk[2] ? -3.0e38f : S[mt][2][r] + bp[32 + ln];
        const float s3 = msk[3] ? -3.0e38f : S[mt][3][r] + bp[48 + ln];
        float mx = fmaxf(fmaxf(s0, s1), fmaxf(s2, s3));
        mx = fmaxf(mx, __shfl_xor(mx, 1)); mx = fmaxf(mx, __shfl_xor(mx, 2));
        mx = fmaxf(mx, __shfl_xor(mx, 4)); mx = fmaxf(mx, __shfl_xor(mx, 8));
        const float mn = fmaxf(mi[mt][r], mx);
        const float a = __expf(mi[mt][r] - mn);
        const float p0 = __expf(s0 - mn), p1 = __expf(s1 - mn);
        const float p2 = __expf(s2 - mn), p3 = __expf(s3 - mn);
        float rs = p0 + p1 + p2 + p3;
        rs += __shfl_xor(rs, 1); rs += __shfl_xor(rs, 2);
        rs += __shfl_xor(rs, 4); rs += __shfl_xor(rs, 8);
        li[mt][r] = li[mt][r] * a + rs;
        mi[mt][r] = mn; alpha[mt][r] = a;
        const int q = wr + mt * 16 + quad * 4 + r;
        Ps[((kcb    ) * 128 + q) * 8 + jj] = f2bf(p0);
        Ps[((kcb + 2) * 128 + q) * 8 + jj] = f2bf(p1);
        Ps[((kcb + 4) * 128 + q) * 8 + jj] = f2bf(p2);
        Ps[((kcb + 6) * 128 + q) * 8 + jj] = f2bf(p3);
      }

#pragma unroll
    for (int mt = 0; mt < 2; ++mt)
#pragma unroll
      for (int nt = 0; nt < 4; ++nt)
#pragma unroll
        for (int r = 0; r < 4; ++r) O[mt][nt][r] *= alpha[mt][r];

#pragma unroll
    for (int ks = 0; ks < 2; ++ks) {
      const short8 pf0 = *(const short8*)&Ps[((ks * 4 + quad) * 128 + wr + ln) * 8];
      const short8 pf1 = *(const short8*)&Ps[((ks * 4 + quad) * 128 + wr + 16 + ln) * 8];
#pragma unroll
      for (int nt = 0; nt < 4; ++nt) {
        const short8 vf = *(const short8*)&Vs[((ks * 4 + quad) * 64 + nt * 16 + ln) * 8];
        O[0][nt] = MFMA16(pf0, vf, O[0][nt]);
        O[1][nt] = MFMA16(pf1, vf, O[1][nt]);
      }
    }
  }

#pragma unroll
  for (int mt = 0; mt < 2; ++mt)
#pragma unroll
    for (int r = 0; r < 4; ++r) {
      const float inv = 1.0f / fmaxf(li[mt][r], 1e-6f);
      const int qg = q0 + wr + mt * 16 + quad * 4 + r;
#pragma unroll
      for (int nt = 0; nt < 4; ++nt)
        ctx[((size_t)(b * Ss + qg)) * 1024 + h * 64 + nt * 16 + ln] =
            f2bf(O[mt][nt][r] * inv);
    }
}

// ---- launch ----------------------------------------------------------------
extern "C" void kernel_launch(void* const* d_in, const int* in_sizes, int n_in,
                              void* d_out, int out_size, void* d_ws, size_t ws_size,
                              hipStream_t stream) {
  const float* query = (const float*)d_in[0];
  const float* key   = (const float*)d_in[1];
  const float* value = (const float*)d_in[2];
  const int*   kpm   = (const int*)d_in[3];
  const float* bias  = (const float*)d_in[4];
  const float* q_w   = (const float*)d_in[5];
  const float* q_b   = (const float*)d_in[6];
  const float* k_w   = (const float*)d_in[7];
  const float* k_b   = (const float*)d_in[8];
  const float* v_w   = (const float*)d_in[9];
  const float* v_b   = (const float*)d_in[10];
  const float* o_w   = (const float*)d_in[11];
  const float* o_b   = (const float*)d_in[12];
  float* out = (float*)d_out;

  char* ws = (char*)d_ws;
  const size_t MB = 1024 * 1024;
  u16* xq = (u16*)(ws + 0 * MB);
  u16* xk = (u16*)(ws + 8 * MB);
  u16* xv = (u16*)(ws + 16 * MB);
  u16* wq = (u16*)(ws + 24 * MB);
  u16* wk = (u16*)(ws + 26 * MB);
  u16* wv = (u16*)(ws + 28 * MB);
  u16* wo = (u16*)(ws + 30 * MB);
  u16* qb = (u16*)(ws + 32 * MB);
  u16* kb = (u16*)(ws + 40 * MB);
  u16* vb = (u16*)(ws + 48 * MB);
  u16* cx = (u16*)(ws + 56 * MB);
  u16* vt = (u16*)(ws + 0 * MB);  // alias xq (dead after gemm_qkv)

  cast3<<<dim3(4096, 1, 3), 256, 0, stream>>>(query, key, value, xq, xk, xv);
  cast4<<<dim3(1024, 1, 4), 256, 0, stream>>>(q_w, k_w, v_w, o_w, wq, wk, wv, wo);
  gemm_qkv<<<dim3(8, 32, 3), 256, 0, stream>>>(xq, xk, xv, wq, wk, wv,
                                               q_b, k_b, v_b, qb, kb, vb);
  transpose_v<<<dim3(32, 32), 256, 0, stream>>>(vb, vt);
  attn<<<dim3(16, 32), 256, 0, stream>>>(qb, kb, vt, bias, kpm, cx);
  gemm_o<<<dim3(8, 32), 256, 0, stream>>>(cx, wo, o_b, out);
}

// Round 3
// 616.914 us; speedup vs baseline: 2.4087x; 1.4914x over previous
//
#include <hip/hip_runtime.h>
#include <math.h>

// B=2, S=2048, H=1024, NH=16, HD=64
#define Ss  2048
#define Hh  1024

typedef unsigned short u16;
typedef __attribute__((ext_vector_type(8))) short short8;
typedef __attribute__((ext_vector_type(4))) float fx4;

__device__ __forceinline__ u16 f2bf(float f) {
  unsigned int u = __float_as_uint(f);
  u = (u + 0x7fffu + ((u >> 16) & 1u)) >> 16;
  return (u16)u;
}

__device__ __forceinline__ void gld_lds16(const u16* g, u16* l) {
  __builtin_amdgcn_global_load_lds(
      (const __attribute__((address_space(1))) unsigned int*)(const unsigned int*)g,
      (__attribute__((address_space(3))) unsigned int*)(unsigned int*)l, 16, 0, 0);
}

#define MFMA16(a,b,c) __builtin_amdgcn_mfma_f32_16x16x32_bf16((a),(b),(c),0,0,0)

// ---- casts -----------------------------------------------------------------
__global__ __launch_bounds__(256) void cast3(const float* __restrict__ a,
    const float* __restrict__ b, const float* __restrict__ c,
    u16* __restrict__ oa, u16* __restrict__ ob, u16* __restrict__ oc) {
  const int z = blockIdx.z;
  const float* in = z == 0 ? a : (z == 1 ? b : c);
  u16* out = z == 0 ? oa : (z == 1 ? ob : oc);
  const int i = (blockIdx.x * 256 + threadIdx.x) * 4;
  const float4 v = *(const float4*)(in + i);
  ushort4 r; r.x = f2bf(v.x); r.y = f2bf(v.y); r.z = f2bf(v.z); r.w = f2bf(v.w);
  *(ushort4*)(out + i) = r;
}

__global__ __launch_bounds__(256) void cast4(const float* __restrict__ a,
    const float* __restrict__ b, const float* __restrict__ c, const float* __restrict__ d,
    u16* __restrict__ oa, u16* __restrict__ ob, u16* __restrict__ oc, u16* __restrict__ od) {
  const int z = blockIdx.z;
  const float* in = z == 0 ? a : (z == 1 ? b : (z == 2 ? c : d));
  u16* out = z == 0 ? oa : (z == 1 ? ob : (z == 2 ? oc : od));
  const int i = (blockIdx.x * 256 + threadIdx.x) * 4;
  const float4 v = *(const float4*)(in + i);
  ushort4 r; r.x = f2bf(v.x); r.y = f2bf(v.y); r.z = f2bf(v.z); r.w = f2bf(v.w);
  *(ushort4*)(out + i) = r;
}

// kpm (int 0/1) -> float additive mask {0, -1e30}
__global__ __launch_bounds__(256) void build_maskadd(const int* __restrict__ kpm,
                                                     float* __restrict__ ma) {
  const int i = blockIdx.x * 256 + threadIdx.x;
  ma[i] = kpm[i] ? -1.0e30f : 0.0f;
}

// ---- GEMM: C[M,N] = A[M,K]@W[N,K]^T + bias, K=N=1024, 128x128 tile --------
template <int MODE>
__device__ __forceinline__ void gemm_core(const u16* __restrict__ A,
    const u16* __restrict__ W, const float* __restrict__ bias,
    void* __restrict__ out, float scale) {
  __shared__ __align__(16) u16 As[4096];
  __shared__ __align__(16) u16 Bs[4096];
  const int tid = threadIdx.x;
  const int w = tid >> 6, lane = tid & 63, ln = lane & 15, quad = lane >> 4;
  const int i0 = blockIdx.y * 128, j0 = blockIdx.x * 128;
  const int wr = (w & 1) * 64, wc = (w >> 1) * 64;
  fx4 acc[4][4] = {};
  const int L0 = w * 64 + lane, L1 = L0 + 256;
  const u16* sa0 = A + (size_t)(i0 + (L0 & 127)) * 1024 + (L0 >> 7) * 8;
  const u16* sa1 = A + (size_t)(i0 + (L1 & 127)) * 1024 + (L1 >> 7) * 8;
  const u16* sb0 = W + (size_t)(j0 + (L0 & 127)) * 1024 + (L0 >> 7) * 8;
  const u16* sb1 = W + (size_t)(j0 + (L1 & 127)) * 1024 + (L1 >> 7) * 8;
  u16* da0 = As + (w * 64) * 8;  u16* da1 = As + (256 + w * 64) * 8;
  u16* db0 = Bs + (w * 64) * 8;  u16* db1 = Bs + (256 + w * 64) * 8;
  for (int k0 = 0; k0 < 1024; k0 += 32) {
    __syncthreads();
    gld_lds16(sa0 + k0, da0); gld_lds16(sa1 + k0, da1);
    gld_lds16(sb0 + k0, db0); gld_lds16(sb1 + k0, db1);
    __syncthreads();
    short8 a[4], b[4];
#pragma unroll
    for (int t = 0; t < 4; ++t) {
      a[t] = *(const short8*)&As[(quad * 128 + wr + t * 16 + ln) * 8];
      b[t] = *(const short8*)&Bs[(quad * 128 + wc + t * 16 + ln) * 8];
    }
#pragma unroll
    for (int mt = 0; mt < 4; ++mt)
#pragma unroll
      for (int nt = 0; nt < 4; ++nt)
        acc[mt][nt] = MFMA16(a[mt], b[nt], acc[mt][nt]);
  }
#pragma unroll
  for (int nt = 0; nt < 4; ++nt) {
    const int col = j0 + wc + nt * 16 + ln;
    const float bv = bias[col];
#pragma unroll
    for (int mt = 0; mt < 4; ++mt)
#pragma unroll
      for (int r = 0; r < 4; ++r) {
        const int row = i0 + wr + mt * 16 + quad * 4 + r;
        const float val = (acc[mt][nt][r] + bv) * scale;
        if (MODE == 1) {
          const int bb = row >> 11, s = row & 2047, h = col >> 6, d = col & 63;
          ((u16*)out)[((size_t)(bb * 16 + h) * 2048 + s) * 64 + d] = f2bf(val);
        } else {
          ((float*)out)[(size_t)row * 1024 + col] = val;
        }
      }
  }
}

__global__ __launch_bounds__(256) void gemm_qkv(
    const u16* xq, const u16* xk, const u16* xv,
    const u16* wq, const u16* wk, const u16* wv,
    const float* bq, const float* bk, const float* bv,
    u16* q, u16* k, u16* v) {
  const int z = blockIdx.z;
  const u16* A = z == 0 ? xq : (z == 1 ? xk : xv);
  const u16* W = z == 0 ? wq : (z == 1 ? wk : wv);
  const float* bb = z == 0 ? bq : (z == 1 ? bk : bv);
  u16* o = z == 0 ? q : (z == 1 ? k : v);
  const float sc = z == 0 ? 0.125f : 1.0f;
  gemm_core<1>(A, W, bb, o, sc);
}

__global__ __launch_bounds__(256) void gemm_o(const u16* ctx, const u16* wo,
                                              const float* ob, float* out) {
  gemm_core<0>(ctx, wo, ob, out, 1.0f);
}

// ---- V transpose: (bh,S,HD) -> (bh,HD,S), bf16 -----------------------------
__global__ __launch_bounds__(256) void transpose_v(const u16* __restrict__ v,
                                                   u16* __restrict__ vt) {
  __shared__ u16 T[64][72];
  const int tid = threadIdx.x;
  const int bh = blockIdx.y, s0 = blockIdx.x * 64;
#pragma unroll
  for (int i = 0; i < 2; ++i) {
    const int L = i * 256 + tid, key = L >> 3, dc = L & 7;
    const uint4 val = *(const uint4*)&v[((size_t)bh * 2048 + s0 + key) * 64 + dc * 8];
    *(uint4*)&T[key][dc * 8] = val;
  }
  __syncthreads();
#pragma unroll
  for (int i = 0; i < 2; ++i) {
    const int L = i * 256 + tid, d = L >> 3, kc = L & 7;
    u16 tmp[8];
#pragma unroll
    for (int j = 0; j < 8; ++j) tmp[j] = T[kc * 8 + j][d];
    *(uint4*)&vt[((size_t)bh * 64 + d) * 2048 + s0 + kc * 8] = *(const uint4*)tmp;
  }
}

// ---- flash attention: 64 q-rows/block (16/wave), 64-key tiles --------------
__global__ __launch_bounds__(256) void attn(const u16* __restrict__ Qb,
    const u16* __restrict__ Kb, const u16* __restrict__ VT,
    const float* __restrict__ bias, const float* __restrict__ maskadd,
    u16* __restrict__ ctx) {
  __shared__ __align__(16) u16 Ks[4096];  // [c0..7][key0..63]*8
  __shared__ __align__(16) u16 Vs[4096];  // [kc0..7][d0..63]*8
  __shared__ __align__(16) u16 Ps[4096];  // [kc0..7][q0..63]*8
  const int tid = threadIdx.x;
  const int w = tid >> 6, lane = tid & 63, ln = lane & 15, quad = lane >> 4;
  const int q0 = blockIdx.x * 64;
  const int hb = blockIdx.y, h = hb >> 1, b = hb & 1, bh = b * 16 + h;
  const int wr = w * 16;            // wave's 16 q-rows within tile

  short8 qf[2];
#pragma unroll
  for (int ks = 0; ks < 2; ++ks)
    qf[ks] = *(const short8*)&Qb[((size_t)bh * 2048 + q0 + wr + ln) * 64 +
                                 ks * 32 + quad * 8];
  float mi[4], li[4];
  fx4 O[4] = {};
#pragma unroll
  for (int r = 0; r < 4; ++r) { mi[r] = -3.0e38f; li[r] = 0.f; }

  const int L0 = w * 64 + lane, L1 = L0 + 256;
  const u16* sk0 = Kb + ((size_t)bh * 2048 + (L0 & 63)) * 64 + (L0 >> 6) * 8;
  const u16* sk1 = Kb + ((size_t)bh * 2048 + (L1 & 63)) * 64 + (L1 >> 6) * 8;
  const u16* sv0 = VT + ((size_t)bh * 64 + (L0 & 63)) * 2048 + (L0 >> 6) * 8;
  const u16* sv1 = VT + ((size_t)bh * 64 + (L1 & 63)) * 2048 + (L1 >> 6) * 8;
  u16* dk0 = Ks + (w * 64) * 8;  u16* dk1 = Ks + (256 + w * 64) * 8;
  u16* dv0 = Vs + (w * 64) * 8;  u16* dv1 = Vs + (256 + w * 64) * 8;

  // bias/mask pipelined one k-tile ahead in registers
  const float* bq = bias + (size_t)h * Ss * Ss;
  float bcur[4][4], macur[4];
#pragma unroll
  for (int r = 0; r < 4; ++r) {
    const int qg = q0 + wr + quad * 4 + r;
#pragma unroll
    for (int nt = 0; nt < 4; ++nt)
      bcur[nt][r] = bq[(size_t)qg * Ss + nt * 16 + ln];
  }
#pragma unroll
  for (int nt = 0; nt < 4; ++nt) macur[nt] = maskadd[b * Ss + nt * 16 + ln];

  for (int kt = 0; kt < Ss; kt += 64) {
    __syncthreads();
    gld_lds16(sk0 + (size_t)kt * 64, dk0);
    gld_lds16(sk1 + (size_t)kt * 64, dk1);
    gld_lds16(sv0 + kt, dv0);
    gld_lds16(sv1 + kt, dv1);
    __syncthreads();

    fx4 S[4] = {};
#pragma unroll
    for (int ks = 0; ks < 2; ++ks)
#pragma unroll
      for (int nt = 0; nt < 4; ++nt) {
        const short8 kf = *(const short8*)&Ks[((ks * 4 + quad) * 64 + nt * 16 + ln) * 8];
        S[nt] = MFMA16(qf[ks], kf, S[nt]);
      }

    float alpha[4];
#pragma unroll
    for (int r = 0; r < 4; ++r) {
      const float s0 = S[0][r] + bcur[0][r] + macur[0];
      const float s1 = S[1][r] + bcur[1][r] + macur[1];
      const float s2 = S[2][r] + bcur[2][r] + macur[2];
      const float s3 = S[3][r] + bcur[3][r] + macur[3];
      float mx = fmaxf(fmaxf(s0, s1), fmaxf(s2, s3));
      mx = fmaxf(mx, __shfl_xor(mx, 1)); mx = fmaxf(mx, __shfl_xor(mx, 2));
      mx = fmaxf(mx, __shfl_xor(mx, 4)); mx = fmaxf(mx, __shfl_xor(mx, 8));
      const float mn = fmaxf(mi[r], mx);
      const float a = __expf(mi[r] - mn);
      const float p0 = __expf(s0 - mn), p1 = __expf(s1 - mn);
      const float p2 = __expf(s2 - mn), p3 = __expf(s3 - mn);
      float rs = p0 + p1 + p2 + p3;
      rs += __shfl_xor(rs, 1); rs += __shfl_xor(rs, 2);
      rs += __shfl_xor(rs, 4); rs += __shfl_xor(rs, 8);
      li[r] = li[r] * a + rs;
      mi[r] = mn; alpha[r] = a;
      const int q = wr + quad * 4 + r;
      const int kcb = ln >> 3, jj = ln & 7;
      Ps[((kcb    ) * 64 + q) * 8 + jj] = f2bf(p0);
      Ps[((kcb + 2) * 64 + q) * 8 + jj] = f2bf(p1);
      Ps[((kcb + 4) * 64 + q) * 8 + jj] = f2bf(p2);
      Ps[((kcb + 6) * 64 + q) * 8 + jj] = f2bf(p3);
    }

    // prefetch next tile's bias/mask (consumed next iteration; hides latency
    // behind PV MFMA + staging + QK of the next tile)
    const int kn = (kt + 64 < Ss) ? kt + 64 : kt;
    float bnxt[4][4], manxt[4];
#pragma unroll
    for (int r = 0; r < 4; ++r) {
      const int qg = q0 + wr + quad * 4 + r;
#pragma unroll
      for (int nt = 0; nt < 4; ++nt)
        bnxt[nt][r] = bq[(size_t)qg * Ss + kn + nt * 16 + ln];
    }
#pragma unroll
    for (int nt = 0; nt < 4; ++nt) manxt[nt] = maskadd[b * Ss + kn + nt * 16 + ln];

#pragma unroll
    for (int nt = 0; nt < 4; ++nt)
#pragma unroll
      for (int r = 0; r < 4; ++r) O[nt][r] *= alpha[r];

#pragma unroll
    for (int ks = 0; ks < 2; ++ks) {
      const short8 pf = *(const short8*)&Ps[((ks * 4 + quad) * 64 + wr + ln) * 8];
#pragma unroll
      for (int nt = 0; nt < 4; ++nt) {
        const short8 vf = *(const short8*)&Vs[((ks * 4 + quad) * 64 + nt * 16 + ln) * 8];
        O[nt] = MFMA16(pf, vf, O[nt]);
      }
    }

#pragma unroll
    for (int r = 0; r < 4; ++r) {
      macur[r] = manxt[r];
#pragma unroll
      for (int nt = 0; nt < 4; ++nt) bcur[nt][r] = bnxt[nt][r];
    }
  }

#pragma unroll
  for (int r = 0; r < 4; ++r) {
    const float inv = 1.0f / fmaxf(li[r], 1e-6f);
    const int qg = q0 + wr + quad * 4 + r;
#pragma unroll
    for (int nt = 0; nt < 4; ++nt)
      ctx[((size_t)(b * Ss + qg)) * 1024 + h * 64 + nt * 16 + ln] =
          f2bf(O[nt][r] * inv);
  }
}

// ---- launch ----------------------------------------------------------------
extern "C" void kernel_launch(void* const* d_in, const int* in_sizes, int n_in,
                              void* d_out, int out_size, void* d_ws, size_t ws_size,
                              hipStream_t stream) {
  const float* query = (const float*)d_in[0];
  const float* key   = (const float*)d_in[1];
  const float* value = (const float*)d_in[2];
  const int*   kpm   = (const int*)d_in[3];
  const float* bias  = (const float*)d_in[4];
  const float* q_w   = (const float*)d_in[5];
  const float* q_b   = (const float*)d_in[6];
  const float* k_w   = (const float*)d_in[7];
  const float* k_b   = (const float*)d_in[8];
  const float* v_w   = (const float*)d_in[9];
  const float* v_b   = (const float*)d_in[10];
  const float* o_w   = (const float*)d_in[11];
  const float* o_b   = (const float*)d_in[12];
  float* out = (float*)d_out;

  char* ws = (char*)d_ws;
  const size_t MB = 1024 * 1024;
  u16* xq = (u16*)(ws + 0 * MB);
  u16* xk = (u16*)(ws + 8 * MB);
  u16* xv = (u16*)(ws + 16 * MB);
  u16* wq = (u16*)(ws + 24 * MB);
  u16* wk = (u16*)(ws + 26 * MB);
  u16* wv = (u16*)(ws + 28 * MB);
  u16* wo = (u16*)(ws + 30 * MB);
  u16* qb = (u16*)(ws + 32 * MB);
  u16* kb = (u16*)(ws + 40 * MB);
  u16* vb = (u16*)(ws + 48 * MB);
  u16* cx = (u16*)(ws + 56 * MB);
  u16* vt = (u16*)(ws + 0 * MB);     // alias xq (dead after gemm_qkv)
  float* ma = (float*)(ws + 8 * MB); // alias xk (dead after gemm_qkv)

  cast3<<<dim3(4096, 1, 3), 256, 0, stream>>>(query, key, value, xq, xk, xv);
  cast4<<<dim3(1024, 1, 4), 256, 0, stream>>>(q_w, k_w, v_w, o_w, wq, wk, wv, wo);
  gemm_qkv<<<dim3(8, 32, 3), 256, 0, stream>>>(xq, xk, xv, wq, wk, wv,
                                               q_b, k_b, v_b, qb, kb, vb);
  transpose_v<<<dim3(32, 32), 256, 0, stream>>>(vb, vt);
  build_maskadd<<<dim3(16), 256, 0, stream>>>(kpm, ma);
  attn<<<dim3(32, 32), 256, 0, stream>>>(qb, kb, vt, bias, ma, cx);
  gemm_o<<<dim3(8, 32), 256, 0, stream>>>(cx, wo, o_b, out);
}